// Round 2
// baseline (261.066 us; speedup 1.0000x reference)
//
#include <hip/hip_runtime.h>

// TreeSoftmax: x [B=4, C=144, H=256, W=256] f32 -> same shape.
// 4-ary tree, node i (1..144) <-> channel i-1. parent(i) = (i-1)/4.
// 36 sibling groups of 4; res[i] = softmax_within_group(x)[i] * res[parent(i)].
//
// R2: one thread per PIXEL (scalar f32). 262144 threads = 1024 blocks of 256
// = 4 waves/SIMD (vs 2 for the f2 variant) — memory-bound kernel, TLP is the
// lever. Loads stay perfectly coalesced (lane i -> consecutive float).
// Nontemporal stores keep the write stream from thrashing L2/L3 (input is
// L3-resident after the harness restore; output is never re-read in-kernel).

__device__ __forceinline__ void grp4s(const float in[4], float pr, float out[4]) {
    float m = fmaxf(fmaxf(in[0], in[1]), fmaxf(in[2], in[3]));
    float e0 = __expf(in[0] - m);
    float e1 = __expf(in[1] - m);
    float e2 = __expf(in[2] - m);
    float e3 = __expf(in[3] - m);
    float f = pr / (e0 + e1 + e2 + e3);   // parent prob folded into normalization
    out[0] = e0 * f;
    out[1] = e1 * f;
    out[2] = e2 * f;
    out[3] = e3 * f;
}

__global__ __launch_bounds__(256) void tree_softmax_kernel(
        const float* __restrict__ x, float* __restrict__ y) {
    const int HW = 256 * 256;          // per-channel pixel count (channel stride)
    const int C  = 144;

    int tid = blockIdx.x * 256 + threadIdx.x;   // 0 .. 262143
    int b   = tid >> 16;                        // 65536 pixels per batch image
    int rem = tid & 65535;
    size_t base = (size_t)b * C * HW + (size_t)rem;   // in floats

    const float* __restrict__ xp = x + base;
    float*       __restrict__ yp = y + base;

    float in[4], o[4];

    // ---- level 1: channels 0..3, parent prob = 1 ----
    float r1[4];
#pragma unroll
    for (int c = 0; c < 4; ++c) in[c] = xp[c * HW];
    grp4s(in, 1.0f, r1);
#pragma unroll
    for (int c = 0; c < 4; ++c) __builtin_nontemporal_store(r1[c], &yp[c * HW]);

    // ---- level 2: parents = nodes 1..4 (r1), children channels 4..19 ----
    float r2[16];
#pragma unroll
    for (int p = 0; p < 4; ++p) {
#pragma unroll
        for (int c = 0; c < 4; ++c) in[c] = xp[(4 + 4 * p + c) * HW];
        grp4s(in, r1[p], o);
#pragma unroll
        for (int c = 0; c < 4; ++c) {
            __builtin_nontemporal_store(o[c], &yp[(4 + 4 * p + c) * HW]);
            r2[4 * p + c] = o[c];
        }
    }

    // ---- level 3: parents = nodes 5..20 (r2), children channels 20..83 ----
    // keep nodes 21..35 (channels 20..34) as level-4 parents
    float keep[15];
#pragma unroll
    for (int p = 0; p < 16; ++p) {
#pragma unroll
        for (int c = 0; c < 4; ++c) in[c] = xp[(20 + 4 * p + c) * HW];
        grp4s(in, r2[p], o);
#pragma unroll
        for (int c = 0; c < 4; ++c) {
            int idx = 4 * p + c;            // 0..63, channel 20+idx
            __builtin_nontemporal_store(o[c], &yp[(20 + idx) * HW]);
            if (idx < 15) keep[idx] = o[c]; // compile-time predicate after unroll
        }
    }

    // ---- level 4: parents = nodes 21..35 (keep), children channels 84..143 ----
#pragma unroll
    for (int p = 0; p < 15; ++p) {
#pragma unroll
        for (int c = 0; c < 4; ++c) in[c] = xp[(84 + 4 * p + c) * HW];
        grp4s(in, keep[p], o);
#pragma unroll
        for (int c = 0; c < 4; ++c)
            __builtin_nontemporal_store(o[c], &yp[(84 + 4 * p + c) * HW]);
    }
}

extern "C" void kernel_launch(void* const* d_in, const int* in_sizes, int n_in,
                              void* d_out, int out_size, void* d_ws, size_t ws_size,
                              hipStream_t stream) {
    const float* x = (const float*)d_in[0];
    float* y = (float*)d_out;
    const int threads = 256;
    const int blocks  = (4 * 256 * 256) / threads;   // 1024 blocks, 1 thread/pixel
    tree_softmax_kernel<<<blocks, threads, 0, stream>>>(x, y);
}

// Round 5
// 259.422 us; speedup vs baseline: 1.0063x; 1.0063x over previous
//
#include <hip/hip_runtime.h>

// TreeSoftmax: x [B=4, C=144, H=256, W=256] f32 -> same shape.
// 4-ary tree, node i (1..144) <-> channel i-1. parent(i) = (i-1)/4.
// 36 sibling groups of 4; res[i] = softmax_group(x)[i] * res[parent(i)].
//
// R3: kernel was LATENCY-bound (95us, 2.3TB/s, VGPR=28 -> ~1 load in flight
// per wave). Fix = memory-level parallelism: issue ALL 144 channel loads
// up front into registers, then compute level-by-level. __launch_bounds__
// (256,1) tells the allocator 1 wave/EU is acceptable so it may keep ~150+
// values live instead of serializing load->use. 4 waves/SIMD from the grid;
// VGPR ~170 caps residency at 2-3/SIMD, each with up to 63 outstanding VMEM.

__device__ __forceinline__ void grp4s(float a, float b, float c, float d,
                                      float pr, float out[4]) {
    float m = fmaxf(fmaxf(a, b), fmaxf(c, d));
    float e0 = __expf(a - m);
    float e1 = __expf(b - m);
    float e2 = __expf(c - m);
    float e3 = __expf(d - m);
    float f = pr / (e0 + e1 + e2 + e3);   // parent prob folded into normalization
    out[0] = e0 * f;
    out[1] = e1 * f;
    out[2] = e2 * f;
    out[3] = e3 * f;
}

__global__ __launch_bounds__(256, 1) void tree_softmax_kernel(
        const float* __restrict__ x, float* __restrict__ y) {
    const int HW = 256 * 256;          // channel stride in floats
    const int C  = 144;

    int tid = blockIdx.x * 256 + threadIdx.x;   // 0 .. 262143
    int b   = tid >> 16;
    int rem = tid & 65535;
    size_t base = (size_t)b * C * HW + (size_t)rem;

    const float* __restrict__ xp = x + base;
    float*       __restrict__ yp = y + base;

    // ---- issue every channel load up front: deep MLP ----
    float v[144];
#pragma unroll
    for (int c = 0; c < 144; ++c) v[c] = xp[c * HW];

    float o[4];

    // ---- level 1: channels 0..3, parent prob = 1 ----
    float r1[4];
    grp4s(v[0], v[1], v[2], v[3], 1.0f, r1);
#pragma unroll
    for (int c = 0; c < 4; ++c) __builtin_nontemporal_store(r1[c], &yp[c * HW]);

    // ---- level 2: parents nodes 1..4 (r1), channels 4..19 ----
    float r2[16];
#pragma unroll
    for (int p = 0; p < 4; ++p) {
        grp4s(v[4 + 4 * p], v[5 + 4 * p], v[6 + 4 * p], v[7 + 4 * p], r1[p], o);
#pragma unroll
        for (int c = 0; c < 4; ++c) {
            __builtin_nontemporal_store(o[c], &yp[(4 + 4 * p + c) * HW]);
            r2[4 * p + c] = o[c];
        }
    }

    // ---- level 3: parents nodes 5..20 (r2), channels 20..83 ----
    // keep channels 20..34 (nodes 21..35) as level-4 parents
    float keep[15];
#pragma unroll
    for (int p = 0; p < 16; ++p) {
        int c0 = 20 + 4 * p;
        grp4s(v[c0], v[c0 + 1], v[c0 + 2], v[c0 + 3], r2[p], o);
#pragma unroll
        for (int c = 0; c < 4; ++c) {
            int idx = 4 * p + c;            // 0..63
            __builtin_nontemporal_store(o[c], &yp[(c0 + c) * HW]);
            if (idx < 15) keep[idx] = o[c]; // compile-time predicate after unroll
        }
    }

    // ---- level 4: parents nodes 21..35 (keep), channels 84..143 ----
#pragma unroll
    for (int p = 0; p < 15; ++p) {
        int c0 = 84 + 4 * p;
        grp4s(v[c0], v[c0 + 1], v[c0 + 2], v[c0 + 3], keep[p], o);
#pragma unroll
        for (int c = 0; c < 4; ++c)
            __builtin_nontemporal_store(o[c], &yp[(c0 + c) * HW]);
    }
}

extern "C" void kernel_launch(void* const* d_in, const int* in_sizes, int n_in,
                              void* d_out, int out_size, void* d_ws, size_t ws_size,
                              hipStream_t stream) {
    const float* x = (const float*)d_in[0];
    float* y = (float*)d_out;
    const int threads = 256;
    const int blocks  = (4 * 256 * 256) / threads;   // 1024 blocks, 1 thread/pixel
    tree_softmax_kernel<<<blocks, threads, 0, stream>>>(x, y);
}